// Round 1
// baseline (270.410 us; speedup 1.0000x reference)
//
#include <hip/hip_runtime.h>

typedef __attribute__((ext_vector_type(8))) short bf16x8;
typedef __attribute__((ext_vector_type(4))) float f32x4;

#define T_SEQ 1024
#define NH 16
#define CEMB 1024

__device__ __forceinline__ float asf(unsigned int u){ union{unsigned int i;float f;}x; x.i=u; return x.f; }
__device__ __forceinline__ float bf2f(unsigned short u){ return asf(((unsigned int)u)<<16); }
__device__ __forceinline__ unsigned short f2bf(float f){
  union{float f;unsigned int i;}x; x.f=f;
  unsigned int r = x.i + 0x7FFFu + ((x.i>>16)&1u);
  return (unsigned short)(r>>16);
}

// ---------------- fp32 -> bf16 convert (vectorized) ----------------
__global__ void cvt_bf16_kernel(const float* __restrict__ in, unsigned short* __restrict__ out, int n){
  int i = (blockIdx.x*blockDim.x + threadIdx.x)*4;
  if (i >= n) return;
  float4 v = *reinterpret_cast<const float4*>(in + i);
  ushort4 o; o.x=f2bf(v.x); o.y=f2bf(v.y); o.z=f2bf(v.z); o.w=f2bf(v.w);
  *reinterpret_cast<ushort4*>(out + i) = o;
}

// ---------------- transpose fp32 [R][C] -> bf16 [C][R] ----------------
__global__ void transpose_bf16_kernel(const float* __restrict__ W, unsigned short* __restrict__ Wt, int R, int C){
  __shared__ float tile[32][33];
  int c0 = blockIdx.x*32, r0 = blockIdx.y*32;
  int tx = threadIdx.x, ty = threadIdx.y;   // (32,8)
  #pragma unroll
  for (int i=0;i<32;i+=8) tile[ty+i][tx] = W[(size_t)(r0+ty+i)*C + c0 + tx];
  __syncthreads();
  #pragma unroll
  for (int i=0;i<32;i+=8) Wt[(size_t)(c0+ty+i)*R + r0 + tx] = f2bf(tile[tx][ty+i]);
}

// ---------------- gates: softmax(x @ Wgate + bgate) over H ----------------
__global__ void gates_kernel(const float* __restrict__ x, const float* __restrict__ Wg,
                             const float* __restrict__ bg, float* __restrict__ gates){
  const int lane = threadIdx.x & 63;
  const int row  = blockIdx.x*4 + (threadIdx.x>>6);
  const float* xr = x + (size_t)row*CEMB;
  float acc[NH];
  #pragma unroll
  for (int h=0;h<NH;h++) acc[h]=0.f;
  for (int i=0;i<CEMB/64;i++){
    float xv = xr[i*64 + lane];
    const float4* wg = reinterpret_cast<const float4*>(Wg + (size_t)(i*64+lane)*NH);
    float4 a=wg[0], b=wg[1], c=wg[2], d=wg[3];
    acc[0]+=xv*a.x; acc[1]+=xv*a.y; acc[2]+=xv*a.z; acc[3]+=xv*a.w;
    acc[4]+=xv*b.x; acc[5]+=xv*b.y; acc[6]+=xv*b.z; acc[7]+=xv*b.w;
    acc[8]+=xv*c.x; acc[9]+=xv*c.y; acc[10]+=xv*c.z; acc[11]+=xv*c.w;
    acc[12]+=xv*d.x; acc[13]+=xv*d.y; acc[14]+=xv*d.z; acc[15]+=xv*d.w;
  }
  #pragma unroll
  for (int h=0;h<NH;h++){
    #pragma unroll
    for (int m=32;m;m>>=1) acc[h] += __shfl_xor(acc[h], m, 64);
  }
  float mx = -1e30f;
  #pragma unroll
  for (int h=0;h<NH;h++){ acc[h] += bg[h]; mx = fmaxf(mx, acc[h]); }
  float s = 0.f;
  #pragma unroll
  for (int h=0;h<NH;h++){ acc[h] = __expf(acc[h]-mx); s += acc[h]; }
  float g = 0.f;
  #pragma unroll
  for (int h=0;h<NH;h++) g = (lane==h) ? acc[h]/s : g;   // avoid dynamic-index scratch
  if (lane < NH) gates[(size_t)row*NH + lane] = g;
}

// ---------------- bf16 MFMA GEMM: C[M][N] = A[M][K] @ Bt[N][K]^T + bias ----------------
// 128x128 tile, BK=64, 4 waves (each 64x64), global_load_lds width-16,
// XOR chunk-swizzle (pre-swizzled global source, swizzled ds_read).
template<bool OUT_BF16>
__global__ __launch_bounds__(256)
void gemm_bt_kernel(const unsigned short* __restrict__ A, const unsigned short* __restrict__ Bt,
                    const float* __restrict__ bias, void* __restrict__ Cptr,
                    int M, int N, int K){
  __shared__ unsigned short lA[128*64];
  __shared__ unsigned short lB[128*64];
  const int tid = threadIdx.x;
  const int wid = tid>>6, lane = tid&63;
  const int nbm = M>>7;
  const int bm = blockIdx.x % nbm, bn = blockIdx.x / nbm;
  const int wr = wid>>1, wc = wid&1;
  f32x4 acc[4][4] = {};

  const unsigned short* gA = A + (size_t)bm*128*K;
  const unsigned short* gB = Bt + (size_t)bn*128*K;
  const int srow = lane>>3;     // row within 8-row chunk
  const int schunk = lane&7;    // 16B chunk within 128B row

  for (int k0=0; k0<K; k0+=64){
    #pragma unroll
    for (int i=0;i<4;i++){
      int rowi = (wid*4+i)*8 + srow;
      int cc = schunk ^ (rowi & 7);            // inverse-swizzled source chunk
      const unsigned short* srcA = gA + (size_t)rowi*K + k0 + cc*8;
      __builtin_amdgcn_global_load_lds((const __attribute__((address_space(1))) void*)srcA,
          (__attribute__((address_space(3))) void*)&lA[(wid*4+i)*512], 16, 0, 0);
      const unsigned short* srcB = gB + (size_t)rowi*K + k0 + cc*8;
      __builtin_amdgcn_global_load_lds((const __attribute__((address_space(1))) void*)srcB,
          (__attribute__((address_space(3))) void*)&lB[(wid*4+i)*512], 16, 0, 0);
    }
    __syncthreads();
    #pragma unroll
    for (int ks=0; ks<2; ks++){
      bf16x8 af[4], bfr[4];
      #pragma unroll
      for (int m=0;m<4;m++){
        int r = wr*64 + m*16 + (lane&15);
        int p = (ks*4 + (lane>>4)) ^ (r&7);    // swizzled chunk
        af[m] = *reinterpret_cast<const bf16x8*>(&lA[r*64 + p*8]);
      }
      #pragma unroll
      for (int n=0;n<4;n++){
        int r = wc*64 + n*16 + (lane&15);
        int p = (ks*4 + (lane>>4)) ^ (r&7);
        bfr[n] = *reinterpret_cast<const bf16x8*>(&lB[r*64 + p*8]);
      }
      #pragma unroll
      for (int m=0;m<4;m++)
        #pragma unroll
        for (int n=0;n<4;n++)
          acc[m][n] = __builtin_amdgcn_mfma_f32_16x16x32_bf16(af[m], bfr[n], acc[m][n], 0,0,0);
    }
    __syncthreads();
  }
  // epilogue: D col = lane&15, row = (lane>>4)*4 + r  (HW-verified mapping)
  const int rq = lane>>4;
  const int cl = lane&15;
  #pragma unroll
  for (int n=0;n<4;n++){
    int col = bn*128 + wc*64 + n*16 + cl;
    float bv = bias[col];
    #pragma unroll
    for (int m=0;m<4;m++){
      int row = bm*128 + wr*64 + m*16 + rq*4;
      #pragma unroll
      for (int r=0;r<4;r++){
        float v = acc[m][n][r] + bv;
        if (OUT_BF16) ((unsigned short*)Cptr)[(size_t)(row+r)*N + col] = f2bf(v);
        else          ((float*)Cptr)[(size_t)(row+r)*N + col] = v;
      }
    }
  }
}

// ---------------- windowed causal attention + gate, one wave per (b,h,t) ----------------
// qk: [B*T][2C] bf16 (q cols 0..1023, k cols 1024..2047), v = k.
__global__ __launch_bounds__(256)
void attn_kernel(const unsigned short* __restrict__ qk, const float* __restrict__ gates,
                 unsigned short* __restrict__ gated){
  __shared__ float p_s[4][T_SEQ];
  __shared__ float q_s[4][64];
  const int wid = threadIdx.x>>6, lane = threadIdx.x&63;
  const int idx = blockIdx.x;
  const int tg = idx & 255;          // T/4 groups
  const int bh = idx >> 8;
  const int b = bh >> 4, h = bh & 15;
  const int t = tg*4 + wid;
  int win = 1024 >> h; if (win < 4) win = 4;
  int j0 = t - win + 1; if (j0 < 0) j0 = 0;
  const int nk = t + 1 - j0;

  const unsigned short* qrow = qk + ((size_t)(b*T_SEQ + t)*2048 + h*64);
  q_s[wid][lane] = bf2f(qrow[lane]);
  __syncthreads();

  // hoist q into registers (compile-time indexed)
  float qreg[64];
  #pragma unroll
  for (int d=0; d<64; d++) qreg[d] = q_s[wid][d];

  const unsigned short* kbase = qk + ((size_t)(b*T_SEQ + j0)*2048 + 1024 + h*64);
  float mloc = -1e30f;
  for (int j=lane; j<nk; j+=64){
    const uint4* kp = reinterpret_cast<const uint4*>(kbase + (size_t)j*2048);
    float s = 0.f;
    #pragma unroll
    for (int c=0;c<8;c++){
      uint4 kv = kp[c];
      s += asf(kv.x<<16)*qreg[c*8+0] + asf(kv.x&0xffff0000u)*qreg[c*8+1];
      s += asf(kv.y<<16)*qreg[c*8+2] + asf(kv.y&0xffff0000u)*qreg[c*8+3];
      s += asf(kv.z<<16)*qreg[c*8+4] + asf(kv.z&0xffff0000u)*qreg[c*8+5];
      s += asf(kv.w<<16)*qreg[c*8+6] + asf(kv.w&0xffff0000u)*qreg[c*8+7];
    }
    s *= 0.125f;                      // 1/sqrt(64)
    p_s[wid][j] = s;
    mloc = fmaxf(mloc, s);
  }
  #pragma unroll
  for (int m=32;m;m>>=1) mloc = fmaxf(mloc, __shfl_xor(mloc, m, 64));
  float ssum = 0.f;
  for (int j=lane; j<nk; j+=64){
    float e = __expf(p_s[wid][j] - mloc);
    p_s[wid][j] = e;
    ssum += e;
  }
  #pragma unroll
  for (int m=32;m;m>>=1) ssum += __shfl_xor(ssum, m, 64);
  __syncthreads();

  // PV: lane owns output dim d=lane; v = k
  const unsigned short* vbase = kbase + lane;
  float acc = 0.f;
  for (int j=0;j<nk;j++){
    acc += p_s[wid][j] * bf2f(vbase[(size_t)j*2048]);
  }
  float g = gates[(size_t)(b*T_SEQ+t)*NH + h];
  float outv = acc * g / ssum;
  gated[(size_t)(b*T_SEQ+t)*CEMB + h*64 + lane] = f2bf(outv);
}

extern "C" void kernel_launch(void* const* d_in, const int* in_sizes, int n_in,
                              void* d_out, int out_size, void* d_ws, size_t ws_size,
                              hipStream_t stream){
  const float* x     = (const float*)d_in[0];
  const float* Wqk   = (const float*)d_in[1];
  const float* bqk   = (const float*)d_in[2];
  const float* Wgate = (const float*)d_in[3];
  const float* bgate = (const float*)d_in[4];
  const float* Wproj = (const float*)d_in[5];
  const float* bproj = (const float*)d_in[6];
  float* out = (float*)d_out;

  // workspace layout (38.25 MB total)
  unsigned short* x_bf   = (unsigned short*)d_ws;                 // 4096*1024 bf16
  unsigned short* WqkT   = x_bf   + (size_t)4096*1024;            // 2048*1024 bf16
  unsigned short* WprojT = WqkT   + (size_t)2048*1024;            // 1024*1024 bf16
  unsigned short* qkb    = WprojT + (size_t)1024*1024;            // 4096*2048 bf16
  unsigned short* gated  = qkb    + (size_t)4096*2048;            // 4096*1024 bf16
  float*          gates  = (float*)(gated + (size_t)4096*1024);   // 4096*16 f32

  cvt_bf16_kernel<<<4096, 256, 0, stream>>>(x, x_bf, 4096*1024);
  dim3 tb(32,8);
  transpose_bf16_kernel<<<dim3(64,32), tb, 0, stream>>>(Wqk,   WqkT,   1024, 2048);
  transpose_bf16_kernel<<<dim3(32,32), tb, 0, stream>>>(Wproj, WprojT, 1024, 1024);
  gates_kernel<<<1024, 256, 0, stream>>>(x, Wgate, bgate, gates);

  gemm_bt_kernel<true ><<<512, 256, 0, stream>>>(x_bf,  WqkT,   bqk,   qkb, 4096, 2048, 1024);
  attn_kernel<<<16384, 256, 0, stream>>>(qkb, gates, gated);
  gemm_bt_kernel<false><<<256, 256, 0, stream>>>(gated, WprojT, bproj, out, 4096, 1024, 1024);
}

// Round 2
// 252.828 us; speedup vs baseline: 1.0695x; 1.0695x over previous
//
#include <hip/hip_runtime.h>

typedef __attribute__((ext_vector_type(8))) short bf16x8;
typedef __attribute__((ext_vector_type(4))) float f32x4;

#define T_SEQ 1024
#define NH 16
#define CEMB 1024

__device__ __forceinline__ float asf(unsigned int u){ union{unsigned int i;float f;}x; x.i=u; return x.f; }
__device__ __forceinline__ float bf2f(unsigned short u){ return asf(((unsigned int)u)<<16); }
__device__ __forceinline__ unsigned short f2bf(float f){
  union{float f;unsigned int i;}x; x.f=f;
  unsigned int r = x.i + 0x7FFFu + ((x.i>>16)&1u);
  return (unsigned short)(r>>16);
}

// ---------------- fp32 -> bf16 convert (vectorized) ----------------
__global__ void cvt_bf16_kernel(const float* __restrict__ in, unsigned short* __restrict__ out, int n){
  int i = (blockIdx.x*blockDim.x + threadIdx.x)*4;
  if (i >= n) return;
  float4 v = *reinterpret_cast<const float4*>(in + i);
  ushort4 o; o.x=f2bf(v.x); o.y=f2bf(v.y); o.z=f2bf(v.z); o.w=f2bf(v.w);
  *reinterpret_cast<ushort4*>(out + i) = o;
}

// ---------------- transpose fp32 [R][C] -> bf16 [C][R] ----------------
__global__ void transpose_bf16_kernel(const float* __restrict__ W, unsigned short* __restrict__ Wt, int R, int C){
  __shared__ float tile[32][33];
  int c0 = blockIdx.x*32, r0 = blockIdx.y*32;
  int tx = threadIdx.x, ty = threadIdx.y;   // (32,8)
  #pragma unroll
  for (int i=0;i<32;i+=8) tile[ty+i][tx] = W[(size_t)(r0+ty+i)*C + c0 + tx];
  __syncthreads();
  #pragma unroll
  for (int i=0;i<32;i+=8) Wt[(size_t)(c0+ty+i)*R + r0 + tx] = f2bf(tile[tx][ty+i]);
}

// ---------------- gates: softmax(x @ Wgate + bgate) over H ----------------
__global__ void gates_kernel(const float* __restrict__ x, const float* __restrict__ Wg,
                             const float* __restrict__ bg, float* __restrict__ gates){
  const int lane = threadIdx.x & 63;
  const int row  = blockIdx.x*4 + (threadIdx.x>>6);
  const float* xr = x + (size_t)row*CEMB;
  float acc[NH];
  #pragma unroll
  for (int h=0;h<NH;h++) acc[h]=0.f;
  for (int i=0;i<CEMB/64;i++){
    float xv = xr[i*64 + lane];
    const float4* wg = reinterpret_cast<const float4*>(Wg + (size_t)(i*64+lane)*NH);
    float4 a=wg[0], b=wg[1], c=wg[2], d=wg[3];
    acc[0]+=xv*a.x; acc[1]+=xv*a.y; acc[2]+=xv*a.z; acc[3]+=xv*a.w;
    acc[4]+=xv*b.x; acc[5]+=xv*b.y; acc[6]+=xv*b.z; acc[7]+=xv*b.w;
    acc[8]+=xv*c.x; acc[9]+=xv*c.y; acc[10]+=xv*c.z; acc[11]+=xv*c.w;
    acc[12]+=xv*d.x; acc[13]+=xv*d.y; acc[14]+=xv*d.z; acc[15]+=xv*d.w;
  }
  #pragma unroll
  for (int h=0;h<NH;h++){
    #pragma unroll
    for (int m=32;m;m>>=1) acc[h] += __shfl_xor(acc[h], m, 64);
  }
  float mx = -1e30f;
  #pragma unroll
  for (int h=0;h<NH;h++){ acc[h] += bg[h]; mx = fmaxf(mx, acc[h]); }
  float s = 0.f;
  #pragma unroll
  for (int h=0;h<NH;h++){ acc[h] = __expf(acc[h]-mx); s += acc[h]; }
  float g = 0.f;
  #pragma unroll
  for (int h=0;h<NH;h++) g = (lane==h) ? acc[h]/s : g;   // avoid dynamic-index scratch
  if (lane < NH) gates[(size_t)row*NH + lane] = g;
}

// ---------------- bf16 MFMA GEMM: C[M][N] = A[M][K] @ Bt[N][K]^T + bias ----------------
// 128x128 tile, BK=64, 4 waves (each 64x64), global_load_lds width-16,
// XOR chunk-swizzle (pre-swizzled global source, swizzled ds_read).
template<bool OUT_BF16>
__global__ __launch_bounds__(256)
void gemm_bt_kernel(const unsigned short* __restrict__ A, const unsigned short* __restrict__ Bt,
                    const float* __restrict__ bias, void* __restrict__ Cptr,
                    int M, int N, int K){
  __shared__ unsigned short lA[128*64];
  __shared__ unsigned short lB[128*64];
  const int tid = threadIdx.x;
  const int wid = tid>>6, lane = tid&63;
  const int nbm = M>>7;
  const int bm = blockIdx.x % nbm, bn = blockIdx.x / nbm;
  const int wr = wid>>1, wc = wid&1;
  f32x4 acc[4][4] = {};

  const unsigned short* gA = A + (size_t)bm*128*K;
  const unsigned short* gB = Bt + (size_t)bn*128*K;
  const int srow = lane>>3;     // row within 8-row chunk
  const int schunk = lane&7;    // 16B chunk within 128B row

  for (int k0=0; k0<K; k0+=64){
    #pragma unroll
    for (int i=0;i<4;i++){
      int rowi = (wid*4+i)*8 + srow;
      int cc = schunk ^ (rowi & 7);            // inverse-swizzled source chunk
      const unsigned short* srcA = gA + (size_t)rowi*K + k0 + cc*8;
      __builtin_amdgcn_global_load_lds((const __attribute__((address_space(1))) void*)srcA,
          (__attribute__((address_space(3))) void*)&lA[(wid*4+i)*512], 16, 0, 0);
      const unsigned short* srcB = gB + (size_t)rowi*K + k0 + cc*8;
      __builtin_amdgcn_global_load_lds((const __attribute__((address_space(1))) void*)srcB,
          (__attribute__((address_space(3))) void*)&lB[(wid*4+i)*512], 16, 0, 0);
    }
    __syncthreads();
    #pragma unroll
    for (int ks=0; ks<2; ks++){
      bf16x8 af[4], bfr[4];
      #pragma unroll
      for (int m=0;m<4;m++){
        int r = wr*64 + m*16 + (lane&15);
        int p = (ks*4 + (lane>>4)) ^ (r&7);    // swizzled chunk
        af[m] = *reinterpret_cast<const bf16x8*>(&lA[r*64 + p*8]);
      }
      #pragma unroll
      for (int n=0;n<4;n++){
        int r = wc*64 + n*16 + (lane&15);
        int p = (ks*4 + (lane>>4)) ^ (r&7);
        bfr[n] = *reinterpret_cast<const bf16x8*>(&lB[r*64 + p*8]);
      }
      #pragma unroll
      for (int m=0;m<4;m++)
        #pragma unroll
        for (int n=0;n<4;n++)
          acc[m][n] = __builtin_amdgcn_mfma_f32_16x16x32_bf16(af[m], bfr[n], acc[m][n], 0,0,0);
    }
    __syncthreads();
  }
  // epilogue: D col = lane&15, row = (lane>>4)*4 + r  (HW-verified mapping)
  const int rq = lane>>4;
  const int cl = lane&15;
  #pragma unroll
  for (int n=0;n<4;n++){
    int col = bn*128 + wc*64 + n*16 + cl;
    float bv = bias[col];
    #pragma unroll
    for (int m=0;m<4;m++){
      int row = bm*128 + wr*64 + m*16 + rq*4;
      #pragma unroll
      for (int r=0;r<4;r++){
        float v = acc[m][n][r] + bv;
        if (OUT_BF16) ((unsigned short*)Cptr)[(size_t)(row+r)*N + col] = f2bf(v);
        else          ((float*)Cptr)[(size_t)(row+r)*N + col] = v;
      }
    }
  }
}

// ---------------- windowed causal attention + gate, one wave per (b,h,t) ----------------
// qk: [B*T][2C] bf16 (q cols 0..1023, k cols 1024..2047), v = k.
__global__ __launch_bounds__(256)
void attn_kernel(const unsigned short* __restrict__ qk, const float* __restrict__ gates,
                 unsigned short* __restrict__ gated){
  __shared__ float p_s[4][T_SEQ];
  __shared__ float q_s[4][64];
  const int wid = threadIdx.x>>6, lane = threadIdx.x&63;
  const int idx = blockIdx.x;
  const int tg = idx & 255;          // T/4 groups
  const int bh = idx >> 8;
  const int b = bh >> 4, h = bh & 15;
  const int t = tg*4 + wid;
  int win = 1024 >> h; if (win < 4) win = 4;
  int j0 = t - win + 1; if (j0 < 0) j0 = 0;
  const int nk = t + 1 - j0;

  const unsigned short* qrow = qk + ((size_t)(b*T_SEQ + t)*2048 + h*64);
  q_s[wid][lane] = bf2f(qrow[lane]);
  __syncthreads();

  // hoist q into registers (compile-time indexed)
  float qreg[64];
  #pragma unroll
  for (int d=0; d<64; d++) qreg[d] = q_s[wid][d];

  const unsigned short* kbase = qk + ((size_t)(b*T_SEQ + j0)*2048 + 1024 + h*64);
  float mloc = -1e30f;
  for (int j=lane; j<nk; j+=64){
    const uint4* kp = reinterpret_cast<const uint4*>(kbase + (size_t)j*2048);
    float s = 0.f;
    #pragma unroll
    for (int c=0;c<8;c++){
      uint4 kv = kp[c];
      s += asf(kv.x<<16)*qreg[c*8+0] + asf(kv.x&0xffff0000u)*qreg[c*8+1];
      s += asf(kv.y<<16)*qreg[c*8+2] + asf(kv.y&0xffff0000u)*qreg[c*8+3];
      s += asf(kv.z<<16)*qreg[c*8+4] + asf(kv.z&0xffff0000u)*qreg[c*8+5];
      s += asf(kv.w<<16)*qreg[c*8+6] + asf(kv.w&0xffff0000u)*qreg[c*8+7];
    }
    s *= 0.125f;                      // 1/sqrt(64)
    p_s[wid][j] = s;
    mloc = fmaxf(mloc, s);
  }
  #pragma unroll
  for (int m=32;m;m>>=1) mloc = fmaxf(mloc, __shfl_xor(mloc, m, 64));
  float ssum = 0.f;
  for (int j=lane; j<nk; j+=64){
    float e = __expf(p_s[wid][j] - mloc);
    p_s[wid][j] = e;
    ssum += e;
  }
  #pragma unroll
  for (int m=32;m;m>>=1) ssum += __shfl_xor(ssum, m, 64);
  __syncthreads();

  // PV: lane owns output dim d=lane; v = k.
  // Unroll x8 with independent accumulator chains so 8 loads are in flight
  // before any use (breaks the serial load-latency chain that made R1 203us).
  const unsigned short* vbase = kbase + lane;
  float a0=0.f,a1=0.f,a2=0.f,a3=0.f,a4=0.f,a5=0.f,a6=0.f,a7=0.f;
  int j = 0;
  for (; j+8<=nk; j+=8){
    unsigned short v0 = vbase[(size_t)(j+0)*2048];
    unsigned short v1 = vbase[(size_t)(j+1)*2048];
    unsigned short v2 = vbase[(size_t)(j+2)*2048];
    unsigned short v3 = vbase[(size_t)(j+3)*2048];
    unsigned short v4 = vbase[(size_t)(j+4)*2048];
    unsigned short v5 = vbase[(size_t)(j+5)*2048];
    unsigned short v6 = vbase[(size_t)(j+6)*2048];
    unsigned short v7 = vbase[(size_t)(j+7)*2048];
    float4 pa = *reinterpret_cast<const float4*>(&p_s[wid][j]);
    float4 pb = *reinterpret_cast<const float4*>(&p_s[wid][j+4]);
    a0 += pa.x * bf2f(v0);
    a1 += pa.y * bf2f(v1);
    a2 += pa.z * bf2f(v2);
    a3 += pa.w * bf2f(v3);
    a4 += pb.x * bf2f(v4);
    a5 += pb.y * bf2f(v5);
    a6 += pb.z * bf2f(v6);
    a7 += pb.w * bf2f(v7);
  }
  for (; j<nk; j++) a0 += p_s[wid][j] * bf2f(vbase[(size_t)j*2048]);
  float acc = ((a0+a1)+(a2+a3)) + ((a4+a5)+(a6+a7));

  float g = gates[(size_t)(b*T_SEQ+t)*NH + h];
  float outv = acc * g / ssum;
  gated[(size_t)(b*T_SEQ+t)*CEMB + h*64 + lane] = f2bf(outv);
}

extern "C" void kernel_launch(void* const* d_in, const int* in_sizes, int n_in,
                              void* d_out, int out_size, void* d_ws, size_t ws_size,
                              hipStream_t stream){
  const float* x     = (const float*)d_in[0];
  const float* Wqk   = (const float*)d_in[1];
  const float* bqk   = (const float*)d_in[2];
  const float* Wgate = (const float*)d_in[3];
  const float* bgate = (const float*)d_in[4];
  const float* Wproj = (const float*)d_in[5];
  const float* bproj = (const float*)d_in[6];
  float* out = (float*)d_out;

  // workspace layout (38.25 MB total)
  unsigned short* x_bf   = (unsigned short*)d_ws;                 // 4096*1024 bf16
  unsigned short* WqkT   = x_bf   + (size_t)4096*1024;            // 2048*1024 bf16
  unsigned short* WprojT = WqkT   + (size_t)2048*1024;            // 1024*1024 bf16
  unsigned short* qkb    = WprojT + (size_t)1024*1024;            // 4096*2048 bf16
  unsigned short* gated  = qkb    + (size_t)4096*2048;            // 4096*1024 bf16
  float*          gates  = (float*)(gated + (size_t)4096*1024);   // 4096*16 f32

  cvt_bf16_kernel<<<4096, 256, 0, stream>>>(x, x_bf, 4096*1024);
  dim3 tb(32,8);
  transpose_bf16_kernel<<<dim3(64,32), tb, 0, stream>>>(Wqk,   WqkT,   1024, 2048);
  transpose_bf16_kernel<<<dim3(32,32), tb, 0, stream>>>(Wproj, WprojT, 1024, 1024);
  gates_kernel<<<1024, 256, 0, stream>>>(x, Wgate, bgate, gates);

  gemm_bt_kernel<true ><<<512, 256, 0, stream>>>(x_bf,  WqkT,   bqk,   qkb, 4096, 2048, 1024);
  attn_kernel<<<16384, 256, 0, stream>>>(qkb, gates, gated);
  gemm_bt_kernel<false><<<256, 256, 0, stream>>>(gated, WprojT, bproj, out, 4096, 1024, 1024);
}

// Round 3
// 167.460 us; speedup vs baseline: 1.6148x; 1.5098x over previous
//
#include <hip/hip_runtime.h>

typedef __attribute__((ext_vector_type(8))) short bf16x8;
typedef __attribute__((ext_vector_type(4))) float f32x4;

#define T_SEQ 1024
#define NH 16
#define CEMB 1024

__device__ __forceinline__ float asf(unsigned int u){ union{unsigned int i;float f;}x; x.i=u; return x.f; }
__device__ __forceinline__ float bf2f(unsigned short u){ return asf(((unsigned int)u)<<16); }
__device__ __forceinline__ unsigned short f2bf(float f){
  union{float f;unsigned int i;}x; x.f=f;
  unsigned int r = x.i + 0x7FFFu + ((x.i>>16)&1u);
  return (unsigned short)(r>>16);
}
__device__ __forceinline__ f32x4 MFMA16(bf16x8 a, bf16x8 b, f32x4 c){
  return __builtin_amdgcn_mfma_f32_16x16x32_bf16(a, b, c, 0,0,0);
}

// ---------------- fp32 -> bf16 convert (vectorized) ----------------
__global__ void cvt_bf16_kernel(const float* __restrict__ in, unsigned short* __restrict__ out, int n){
  int i = (blockIdx.x*blockDim.x + threadIdx.x)*4;
  if (i >= n) return;
  float4 v = *reinterpret_cast<const float4*>(in + i);
  ushort4 o; o.x=f2bf(v.x); o.y=f2bf(v.y); o.z=f2bf(v.z); o.w=f2bf(v.w);
  *reinterpret_cast<ushort4*>(out + i) = o;
}

// ---------------- transpose fp32 [R][C] -> bf16 [C][R] ----------------
__global__ void transpose_bf16_kernel(const float* __restrict__ W, unsigned short* __restrict__ Wt, int R, int C){
  __shared__ float tile[32][33];
  int c0 = blockIdx.x*32, r0 = blockIdx.y*32;
  int tx = threadIdx.x, ty = threadIdx.y;   // (32,8)
  #pragma unroll
  for (int i=0;i<32;i+=8) tile[ty+i][tx] = W[(size_t)(r0+ty+i)*C + c0 + tx];
  __syncthreads();
  #pragma unroll
  for (int i=0;i<32;i+=8) Wt[(size_t)(c0+ty+i)*R + r0 + tx] = f2bf(tile[tx][ty+i]);
}

// ---------------- gates: softmax(x @ Wgate + bgate) over H ----------------
__global__ void gates_kernel(const float* __restrict__ x, const float* __restrict__ Wg,
                             const float* __restrict__ bg, float* __restrict__ gates){
  const int lane = threadIdx.x & 63;
  const int row  = blockIdx.x*4 + (threadIdx.x>>6);
  const float* xr = x + (size_t)row*CEMB;
  float acc[NH];
  #pragma unroll
  for (int h=0;h<NH;h++) acc[h]=0.f;
  for (int i=0;i<CEMB/64;i++){
    float xv = xr[i*64 + lane];
    const float4* wg = reinterpret_cast<const float4*>(Wg + (size_t)(i*64+lane)*NH);
    float4 a=wg[0], b=wg[1], c=wg[2], d=wg[3];
    acc[0]+=xv*a.x; acc[1]+=xv*a.y; acc[2]+=xv*a.z; acc[3]+=xv*a.w;
    acc[4]+=xv*b.x; acc[5]+=xv*b.y; acc[6]+=xv*b.z; acc[7]+=xv*b.w;
    acc[8]+=xv*c.x; acc[9]+=xv*c.y; acc[10]+=xv*c.z; acc[11]+=xv*c.w;
    acc[12]+=xv*d.x; acc[13]+=xv*d.y; acc[14]+=xv*d.z; acc[15]+=xv*d.w;
  }
  #pragma unroll
  for (int h=0;h<NH;h++){
    #pragma unroll
    for (int m=32;m;m>>=1) acc[h] += __shfl_xor(acc[h], m, 64);
  }
  float mx = -1e30f;
  #pragma unroll
  for (int h=0;h<NH;h++){ acc[h] += bg[h]; mx = fmaxf(mx, acc[h]); }
  float s = 0.f;
  #pragma unroll
  for (int h=0;h<NH;h++){ acc[h] = __expf(acc[h]-mx); s += acc[h]; }
  float g = 0.f;
  #pragma unroll
  for (int h=0;h<NH;h++) g = (lane==h) ? acc[h]/s : g;   // avoid dynamic-index scratch
  if (lane < NH) gates[(size_t)row*NH + lane] = g;
}

// ---------------- bf16 MFMA GEMM: C[M][N] = A[M][K] @ Bt[N][K]^T + bias ----------------
template<bool OUT_BF16>
__global__ __launch_bounds__(256)
void gemm_bt_kernel(const unsigned short* __restrict__ A, const unsigned short* __restrict__ Bt,
                    const float* __restrict__ bias, void* __restrict__ Cptr,
                    int M, int N, int K){
  __shared__ unsigned short lA[128*64];
  __shared__ unsigned short lB[128*64];
  const int tid = threadIdx.x;
  const int wid = tid>>6, lane = tid&63;
  const int nbm = M>>7;
  const int bm = blockIdx.x % nbm, bn = blockIdx.x / nbm;
  const int wr = wid>>1, wc = wid&1;
  f32x4 acc[4][4] = {};

  const unsigned short* gA = A + (size_t)bm*128*K;
  const unsigned short* gB = Bt + (size_t)bn*128*K;
  const int srow = lane>>3;     // row within 8-row chunk
  const int schunk = lane&7;    // 16B chunk within 128B row

  for (int k0=0; k0<K; k0+=64){
    #pragma unroll
    for (int i=0;i<4;i++){
      int rowi = (wid*4+i)*8 + srow;
      int cc = schunk ^ (rowi & 7);            // inverse-swizzled source chunk
      const unsigned short* srcA = gA + (size_t)rowi*K + k0 + cc*8;
      __builtin_amdgcn_global_load_lds((const __attribute__((address_space(1))) void*)srcA,
          (__attribute__((address_space(3))) void*)&lA[(wid*4+i)*512], 16, 0, 0);
      const unsigned short* srcB = gB + (size_t)rowi*K + k0 + cc*8;
      __builtin_amdgcn_global_load_lds((const __attribute__((address_space(1))) void*)srcB,
          (__attribute__((address_space(3))) void*)&lB[(wid*4+i)*512], 16, 0, 0);
    }
    __syncthreads();
    #pragma unroll
    for (int ks=0; ks<2; ks++){
      bf16x8 af[4], bfr[4];
      #pragma unroll
      for (int m=0;m<4;m++){
        int r = wr*64 + m*16 + (lane&15);
        int p = (ks*4 + (lane>>4)) ^ (r&7);    // swizzled chunk
        af[m] = *reinterpret_cast<const bf16x8*>(&lA[r*64 + p*8]);
      }
      #pragma unroll
      for (int n=0;n<4;n++){
        int r = wc*64 + n*16 + (lane&15);
        int p = (ks*4 + (lane>>4)) ^ (r&7);
        bfr[n] = *reinterpret_cast<const bf16x8*>(&lB[r*64 + p*8]);
      }
      #pragma unroll
      for (int m=0;m<4;m++)
        #pragma unroll
        for (int n=0;n<4;n++)
          acc[m][n] = __builtin_amdgcn_mfma_f32_16x16x32_bf16(af[m], bfr[n], acc[m][n], 0,0,0);
    }
    __syncthreads();
  }
  const int rq = lane>>4;
  const int cl = lane&15;
  #pragma unroll
  for (int n=0;n<4;n++){
    int col = bn*128 + wc*64 + n*16 + cl;
    float bv = bias[col];
    #pragma unroll
    for (int m=0;m<4;m++){
      int row = bm*128 + wr*64 + m*16 + rq*4;
      #pragma unroll
      for (int r=0;r<4;r++){
        float v = acc[m][n][r] + bv;
        if (OUT_BF16) ((unsigned short*)Cptr)[(size_t)(row+r)*N + col] = f2bf(v);
        else          ((float*)Cptr)[(size_t)(row+r)*N + col] = v;
      }
    }
  }
}

// ---------------- MFMA flash attention with per-head windows + gate ----------------
// Block = 4 waves, handles (b, h, 64 q-rows). Wave owns 16 q-rows.
// Per 32-row K-tile: stage K in LDS (chunk-XOR swizzle), build V^T in LDS,
// QK^T (4 MFMA), masked online softmax, P->bf16->LDS, PV (4 MFMA). v = k.
__global__ __launch_bounds__(256)
void attn_mfma_kernel(const unsigned short* __restrict__ qk, const float* __restrict__ gates,
                      unsigned short* __restrict__ gated){
  __shared__ unsigned short lK[32*64];      // K-tile row-major, chunk-swizzled
  __shared__ unsigned short lV[64*40];      // V^T [d][kk], rows padded to 40
  __shared__ unsigned short lP[4][16*40];   // per-wave P [q][kk], rows padded to 40

  const int tid = threadIdx.x;
  const int wid = tid>>6, lane = tid&63;
  const int g = lane>>4, li = lane&15;
  const int blk = blockIdx.x;
  const int qt = blk & 15;
  const int bh = blk >> 4;
  const int b = bh >> 4, h = bh & 15;
  int w = 1024 >> h; if (w < 4) w = 4;
  const int q0 = qt*64;
  const int qw0 = q0 + wid*16;

  // Q A-fragments: lane -> row qw0+li, d = g*8..+7 (frag0) and 32+g*8..+7 (frag1)
  const unsigned short* qbase = qk + ((size_t)(b*T_SEQ + qw0 + li)*2048 + h*64 + g*8);
  const bf16x8 aq0 = *reinterpret_cast<const bf16x8*>(qbase);
  const bf16x8 aq1 = *reinterpret_cast<const bf16x8*>(qbase + 32);

  f32x4 oacc[4] = {};
  float mrow[4] = {-1e30f,-1e30f,-1e30f,-1e30f};
  float srow[4] = {0.f,0.f,0.f,0.f};

  int lo = q0 - w + 1; if (lo < 0) lo = 0;
  const int kt_lo = lo >> 5;
  const int kt_hi = (q0 + 63) >> 5;
  int mylo = qw0 - w + 1; if (mylo < 0) mylo = 0;
  const int myhi = qw0 + 15;

  // staging: thread loads K row skk (0..31), d-chunk sc (16B)
  const int skk = tid>>3, sc = tid&7;
  const unsigned short* kstage = qk + ((size_t)b*T_SEQ*2048 + 1024 + h*64 + sc*8);
  const int vd = lane;          // lV build: wave builds kk-chunk wid, lane covers d=lane

  for (int kt = kt_lo; kt <= kt_hi; ++kt){
    const int k0 = kt*32;
    // ---- stage K-tile ----
    const uint4 kv = *reinterpret_cast<const uint4*>(kstage + (size_t)(k0 + skk)*2048);
    *reinterpret_cast<uint4*>(&lK[skk*64 + ((sc ^ (skk&7))<<3)]) = kv;
    __syncthreads();
    // ---- build V^T from lK (swizzle-aware gather, ~2-way banks) ----
    {
      unsigned short vv[8];
      #pragma unroll
      for (int e=0;e<8;e++){
        // element (kk = wid*8+e, d = vd); kk&7 == e
        vv[e] = lK[(wid*8+e)*64 + (((vd>>3) ^ e)<<3) + (vd&7)];
      }
      *reinterpret_cast<uint4*>(&lV[vd*40 + wid*8]) = *reinterpret_cast<const uint4*>(vv);
    }
    const bool active = (k0 <= myhi) && (k0 + 31 >= mylo);
    if (active){
      // ---- QK^T: S[16q x 32kk] as two 16x16 tiles ----
      f32x4 s0 = {}, s1 = {};
      {
        bf16x8 b0 = *reinterpret_cast<const bf16x8*>(&lK[ li*64     + (((g  ) ^ (li&7))<<3)]);
        bf16x8 b1 = *reinterpret_cast<const bf16x8*>(&lK[(16+li)*64 + (((g  ) ^ (li&7))<<3)]);
        s0 = MFMA16(aq0, b0, s0);
        s1 = MFMA16(aq0, b1, s1);
        bf16x8 b2 = *reinterpret_cast<const bf16x8*>(&lK[ li*64     + (((4+g) ^ (li&7))<<3)]);
        bf16x8 b3 = *reinterpret_cast<const bf16x8*>(&lK[(16+li)*64 + (((4+g) ^ (li&7))<<3)]);
        s0 = MFMA16(aq1, b2, s0);
        s1 = MFMA16(aq1, b3, s1);
      }
      // ---- masked online softmax (rows rq = g*4+r, col = li / li+16) ----
      float p0[4], p1[4], tmx[4];
      bool v0[4], v1[4];
      #pragma unroll
      for (int r=0;r<4;r++){
        const int t = qw0 + g*4 + r;
        const int ka = k0 + li;
        const int kb2 = ka + 16;
        v0[r] = (ka <= t) && (ka > t - w);
        v1[r] = (kb2 <= t) && (kb2 > t - w);
        p0[r] = v0[r] ? s0[r]*0.125f : -1e30f;
        p1[r] = v1[r] ? s1[r]*0.125f : -1e30f;
        tmx[r] = fmaxf(p0[r], p1[r]);
      }
      #pragma unroll
      for (int msk=1; msk<16; msk<<=1){
        #pragma unroll
        for (int r=0;r<4;r++) tmx[r] = fmaxf(tmx[r], __shfl_xor(tmx[r], msk, 64));
      }
      float rs[4];
      #pragma unroll
      for (int r=0;r<4;r++){
        const float mn = fmaxf(mrow[r], tmx[r]);
        const float sc2 = __expf(mrow[r] - mn);
        mrow[r] = mn;
        p0[r] = v0[r] ? __expf(p0[r] - mn) : 0.f;
        p1[r] = v1[r] ? __expf(p1[r] - mn) : 0.f;
        rs[r] = p0[r] + p1[r];
        srow[r] *= sc2;
        oacc[0][r] *= sc2; oacc[1][r] *= sc2; oacc[2][r] *= sc2; oacc[3][r] *= sc2;
      }
      #pragma unroll
      for (int msk=1; msk<16; msk<<=1){
        #pragma unroll
        for (int r=0;r<4;r++) rs[r] += __shfl_xor(rs[r], msk, 64);
      }
      #pragma unroll
      for (int r=0;r<4;r++){
        srow[r] += rs[r];
        const int q = g*4 + r;
        lP[wid][q*40 + li]      = f2bf(p0[r]);
        lP[wid][q*40 + 16 + li] = f2bf(p1[r]);
      }
    }
    __syncthreads();   // lV complete (all waves), lP (own wave) complete
    if (active){
      // ---- PV: O[16q x 64d] += P[16x32] * V[32x64] ----
      const bf16x8 pa = *reinterpret_cast<const bf16x8*>(&lP[wid][li*40 + g*8]);
      #pragma unroll
      for (int d4=0; d4<4; d4++){
        const bf16x8 bv = *reinterpret_cast<const bf16x8*>(&lV[(d4*16+li)*40 + g*8]);
        oacc[d4] = MFMA16(pa, bv, oacc[d4]);
      }
    }
  }

  // ---- epilogue: divide by sum, apply gate, store bf16 ----
  #pragma unroll
  for (int r=0;r<4;r++){
    const int t = qw0 + g*4 + r;
    const float gv = gates[(size_t)(b*T_SEQ + t)*NH + h];
    const float inv = gv / srow[r];
    unsigned short* orow = gated + (size_t)(b*T_SEQ + t)*CEMB + h*64 + li;
    orow[0]  = f2bf(oacc[0][r]*inv);
    orow[16] = f2bf(oacc[1][r]*inv);
    orow[32] = f2bf(oacc[2][r]*inv);
    orow[48] = f2bf(oacc[3][r]*inv);
  }
}

extern "C" void kernel_launch(void* const* d_in, const int* in_sizes, int n_in,
                              void* d_out, int out_size, void* d_ws, size_t ws_size,
                              hipStream_t stream){
  const float* x     = (const float*)d_in[0];
  const float* Wqk   = (const float*)d_in[1];
  const float* bqk   = (const float*)d_in[2];
  const float* Wgate = (const float*)d_in[3];
  const float* bgate = (const float*)d_in[4];
  const float* Wproj = (const float*)d_in[5];
  const float* bproj = (const float*)d_in[6];
  float* out = (float*)d_out;

  // workspace layout
  unsigned short* x_bf   = (unsigned short*)d_ws;                 // 4096*1024 bf16
  unsigned short* WqkT   = x_bf   + (size_t)4096*1024;            // 2048*1024 bf16
  unsigned short* WprojT = WqkT   + (size_t)2048*1024;            // 1024*1024 bf16
  unsigned short* qkb    = WprojT + (size_t)1024*1024;            // 4096*2048 bf16
  unsigned short* gated  = qkb    + (size_t)4096*2048;            // 4096*1024 bf16
  float*          gates  = (float*)(gated + (size_t)4096*1024);   // 4096*16 f32

  cvt_bf16_kernel<<<4096, 256, 0, stream>>>(x, x_bf, 4096*1024);
  dim3 tb(32,8);
  transpose_bf16_kernel<<<dim3(64,32), tb, 0, stream>>>(Wqk,   WqkT,   1024, 2048);
  transpose_bf16_kernel<<<dim3(32,32), tb, 0, stream>>>(Wproj, WprojT, 1024, 1024);
  gates_kernel<<<1024, 256, 0, stream>>>(x, Wgate, bgate, gates);

  gemm_bt_kernel<true ><<<512, 256, 0, stream>>>(x_bf,  WqkT,   bqk,   qkb, 4096, 2048, 1024);
  attn_mfma_kernel<<<1024, 256, 0, stream>>>(qkb, gates, gated);
  gemm_bt_kernel<false><<<256, 256, 0, stream>>>(gated, WprojT, bproj, out, 4096, 1024, 1024);
}